// Round 1
// baseline (279.987 us; speedup 1.0000x reference)
//
#include <hip/hip_runtime.h>
#include <stdint.h>

typedef unsigned short u16;
typedef __attribute__((ext_vector_type(8))) short bf16x8;
typedef __attribute__((ext_vector_type(4))) float f32x4;
typedef __attribute__((ext_vector_type(4))) unsigned short u16x4;

// async global->LDS, 16B per lane, dest = wave-uniform base + lane*16
#define GLD16(gp, lp) __builtin_amdgcn_global_load_lds( \
    (__attribute__((address_space(1))) void*)(void*)(gp), \
    (__attribute__((address_space(3))) void*)(void*)(lp), 16, 0, 0)

__device__ __forceinline__ u16 f2b(float f) {  // fp32 -> bf16 bits, RNE
  union { float f; unsigned u; } v; v.f = f;
  unsigned r = v.u + 0x7FFFu + ((v.u >> 16) & 1u);
  return (u16)(r >> 16);
}

// ---------------- weight fp32 -> bf16 ----------------
__global__ __launch_bounds__(256) void cvt_kernel(const float* __restrict__ w,
                                                  u16* __restrict__ o, int n4) {
  int i = blockIdx.x * 256 + threadIdx.x;
  if (i < n4) {
    const float4 f = ((const float4*)w)[i];
    u16x4 r; r[0] = f2b(f.x); r[1] = f2b(f.y); r[2] = f2b(f.z); r[3] = f2b(f.w);
    *(u16x4*)(o + (size_t)i * 4) = r;
  }
}

// ---------------- GroupNorm + transpose to h[B,S,C] bf16 ----------------
// grid = B*32 groups, block = 256. Each block: 16 ch x 1024 spatial.
__global__ __launch_bounds__(256) void gn_kernel(const float* __restrict__ x,
                                                 const float* __restrict__ gw,
                                                 const float* __restrict__ gb,
                                                 u16* __restrict__ h) {
  const int b = blockIdx.x >> 5, g = blockIdx.x & 31;
  const float* xg = x + ((size_t)(b * 512 + g * 16)) * 1024;
  const int tid = threadIdx.x;
  float vals[64];
  float s = 0.f, ss = 0.f;
#pragma unroll
  for (int i = 0; i < 64; i++) {
    float vv = xg[i * 256 + tid];
    vals[i] = vv; s += vv; ss += vv * vv;
  }
#pragma unroll
  for (int off = 32; off; off >>= 1) { s += __shfl_down(s, off); ss += __shfl_down(ss, off); }
  __shared__ float red[8];
  const int wid = tid >> 6, lane = tid & 63;
  if (lane == 0) { red[wid] = s; red[4 + wid] = ss; }
  __syncthreads();
  if (tid == 0) {
    float S = red[0] + red[1] + red[2] + red[3];
    float SS = red[4] + red[5] + red[6] + red[7];
    float mean = S * (1.f / 16384.f);
    float var = SS * (1.f / 16384.f) - mean * mean;
    red[0] = mean; red[1] = rsqrtf(var + 1e-5f);
  }
  __syncthreads();
  const float mean = red[0], rs = red[1];
#pragma unroll
  for (int i = 0; i < 64; i++) {
    const int ch = i >> 2;                 // (i*256+tid)>>10
    const int sp = (i * 256 + tid) & 1023;
    const float sc = gw[g * 16 + ch], bi = gb[g * 16 + ch];
    const float vv = (vals[i] - mean) * rs * sc + bi;
    h[((size_t)(b * 1024 + sp)) * 512 + g * 16 + ch] = f2b(vv);
  }
}

// ---------------- QKV GEMM: qkv[s,o] = sum_c h[s,c] * W[o,c] + bias ----------------
// 128x128 tile, BK=32, 4 waves (2x2), each wave 4x4 MFMA 16x16x32.
__global__ __launch_bounds__(256) void qkv_gemm(const u16* __restrict__ h,
                                                const u16* __restrict__ w,
                                                const float* __restrict__ bias,
                                                u16* __restrict__ q,
                                                u16* __restrict__ k,
                                                u16* __restrict__ v) {
  __shared__ u16 As[128 * 32];
  __shared__ u16 Bs[128 * 32];
  const int b = blockIdx.z;
  const int bm = blockIdx.x;   // s tiles: 0..7
  const int bn = blockIdx.y;   // o tiles: 0..11
  const int tid = threadIdx.x, lane = tid & 63, wid = tid >> 6;
  const int wm = wid & 1, wn = wid >> 1;
  const u16* gA = h + ((size_t)b * 1024 + bm * 128) * 512;
  const u16* gB = w + (size_t)bn * 128 * 512;

  const f32x4 fz = {0.f, 0.f, 0.f, 0.f};
  f32x4 acc[4][4];
#pragma unroll
  for (int i = 0; i < 4; i++)
#pragma unroll
    for (int j = 0; j < 4; j++) acc[i][j] = fz;

  const int r0 = lane >> 2;          // row within 16-row chunk
  const int ch8 = (lane & 3) * 8;    // k offset (elements)

  for (int kt = 0; kt < 16; ++kt) {
    __syncthreads();
#pragma unroll
    for (int j = 0; j < 2; ++j) {
      const int idx = wid * 2 + j;          // 0..7, 16 rows each
      const int row = idx * 16 + r0;
      GLD16(gA + (size_t)row * 512 + kt * 32 + ch8, &As[idx * 512 + lane * 8]);
      GLD16(gB + (size_t)row * 512 + kt * 32 + ch8, &Bs[idx * 512 + lane * 8]);
    }
    __syncthreads();
    bf16x8 af[4], bf[4];
#pragma unroll
    for (int mi = 0; mi < 4; mi++)
      af[mi] = *(const bf16x8*)&As[(wm * 64 + mi * 16 + (lane & 15)) * 32 + (lane >> 4) * 8];
#pragma unroll
    for (int ni = 0; ni < 4; ni++)
      bf[ni] = *(const bf16x8*)&Bs[(wn * 64 + ni * 16 + (lane & 15)) * 32 + (lane >> 4) * 8];
#pragma unroll
    for (int mi = 0; mi < 4; mi++)
#pragma unroll
      for (int ni = 0; ni < 4; ni++)
        acc[mi][ni] = __builtin_amdgcn_mfma_f32_16x16x32_bf16(af[mi], bf[ni], acc[mi][ni], 0, 0, 0);
  }

  // epilogue: scatter into q/k/v [B,8,S,64], scale q,k by 64^-0.25
  const float scale = 0.35355339059327373f;
  const int quad4 = (lane >> 4) << 2;
#pragma unroll
  for (int mi = 0; mi < 4; mi++) {
    const int m = bm * 128 + wm * 64 + mi * 16 + quad4;  // s row (plus r)
#pragma unroll
    for (int ni = 0; ni < 4; ni++) {
      const int n = bn * 128 + wn * 64 + ni * 16 + (lane & 15);  // o in [0,1536)
      const int head = n / 192;
      const int rr = n - head * 192;
      const float bi = bias[n];
      u16* dst; float sc;
      if (rr < 64)       { dst = q; sc = scale; }
      else if (rr < 128) { dst = k; sc = scale; }
      else               { dst = v; sc = 1.0f; }
      const int d = rr & 63;
      dst += ((size_t)(b * 8 + head) * 1024 + m) * 64 + d;
#pragma unroll
      for (int r = 0; r < 4; r++)
        dst[(size_t)r * 64] = f2b((acc[mi][ni][r] + bi) * sc);
    }
  }
}

// ---------------- flash attention ----------------
// grid = (B*H=128, S/256=4). 4 waves; each wave owns 64 Q rows. K/V tiles of 64.
__global__ __launch_bounds__(256, 2) void attn_kernel(const u16* __restrict__ q,
                                                      const u16* __restrict__ k,
                                                      const u16* __restrict__ v,
                                                      u16* __restrict__ o) {
  __shared__ u16 Ks[64 * 72];       // [key][d], stride 72 (pad kills bank conflicts)
  __shared__ u16 Vt[64 * 72];       // [d][key]
  __shared__ u16 Ps[4][64 * 72];    // per-wave P [m][key]
  const int bh = blockIdx.x;        // b*8+h
  const int qb = blockIdx.y;        // 0..3
  const int tid = threadIdx.x, lane = tid & 63, wid = tid >> 6;
  const u16* Q = q + (size_t)bh * 1024 * 64;
  const u16* K = k + (size_t)bh * 1024 * 64;
  const u16* V = v + (size_t)bh * 1024 * 64;
  const int qrow0 = qb * 256 + wid * 64;
  const int c15 = lane & 15, quad = lane >> 4;

  bf16x8 qf[2][4];
#pragma unroll
  for (int kk = 0; kk < 2; kk++)
#pragma unroll
    for (int mi = 0; mi < 4; mi++)
      qf[kk][mi] = *(const bf16x8*)(Q + (size_t)(qrow0 + mi * 16 + c15) * 64 + kk * 32 + quad * 8);

  const f32x4 fz = {0.f, 0.f, 0.f, 0.f};
  f32x4 oacc[4][4];
  float m_run[4][4], l_run[4][4];
#pragma unroll
  for (int i = 0; i < 4; i++)
#pragma unroll
    for (int j = 0; j < 4; j++) { oacc[i][j] = fz; m_run[i][j] = -1e30f; l_run[i][j] = 0.f; }

  u16* P = Ps[wid];

  for (int kt = 0; kt < 16; ++kt) {
    __syncthreads();
    // stage K (row-major, stride 72) and V transposed
#pragma unroll
    for (int p = 0; p < 2; p++) {
      const int key = (tid >> 3) + p * 32;
      const int d0 = (tid & 7) * 8;
      bf16x8 kv = *(const bf16x8*)(K + (size_t)(kt * 64 + key) * 64 + d0);
      *(bf16x8*)&Ks[key * 72 + d0] = kv;
      bf16x8 vv = *(const bf16x8*)(V + (size_t)(kt * 64 + key) * 64 + d0);
#pragma unroll
      for (int j = 0; j < 8; j++) Vt[(d0 + j) * 72 + key] = (u16)vv[j];
    }
    __syncthreads();

    // S = Q K^T   (64x64 per wave)
    f32x4 sacc[4][4];
#pragma unroll
    for (int i = 0; i < 4; i++)
#pragma unroll
      for (int j = 0; j < 4; j++) sacc[i][j] = fz;
#pragma unroll
    for (int kk = 0; kk < 2; kk++) {
      bf16x8 kf[4];
#pragma unroll
      for (int ni = 0; ni < 4; ni++)
        kf[ni] = *(const bf16x8*)&Ks[(ni * 16 + c15) * 72 + kk * 32 + quad * 8];
#pragma unroll
      for (int mi = 0; mi < 4; mi++)
#pragma unroll
        for (int ni = 0; ni < 4; ni++)
          sacc[mi][ni] = __builtin_amdgcn_mfma_f32_16x16x32_bf16(qf[kk][mi], kf[ni], sacc[mi][ni], 0, 0, 0);
    }

    // online softmax: lane owns rows mi*16 + quad*4 + r
#pragma unroll
    for (int mi = 0; mi < 4; mi++) {
#pragma unroll
      for (int r = 0; r < 4; r++) {
        float mx = fmaxf(fmaxf(sacc[mi][0][r], sacc[mi][1][r]), fmaxf(sacc[mi][2][r], sacc[mi][3][r]));
#pragma unroll
        for (int off = 1; off < 16; off <<= 1) mx = fmaxf(mx, __shfl_xor(mx, off));
        const float mnew = fmaxf(m_run[mi][r], mx);
        const float alpha = __expf(m_run[mi][r] - mnew);
        float rsum = 0.f;
#pragma unroll
        for (int ni = 0; ni < 4; ni++) {
          const float p = __expf(sacc[mi][ni][r] - mnew);
          rsum += p;
          P[(mi * 16 + quad * 4 + r) * 72 + ni * 16 + c15] = f2b(p);
        }
#pragma unroll
        for (int off = 1; off < 16; off <<= 1) rsum += __shfl_xor(rsum, off);
        l_run[mi][r] = l_run[mi][r] * alpha + rsum;
        m_run[mi][r] = mnew;
#pragma unroll
        for (int nd = 0; nd < 4; nd++) oacc[mi][nd][r] *= alpha;
      }
    }

    // O += P V
#pragma unroll
    for (int kk = 0; kk < 2; kk++) {
      bf16x8 pf[4], vf[4];
#pragma unroll
      for (int mi = 0; mi < 4; mi++)
        pf[mi] = *(const bf16x8*)&P[(mi * 16 + c15) * 72 + kk * 32 + quad * 8];
#pragma unroll
      for (int nd = 0; nd < 4; nd++)
        vf[nd] = *(const bf16x8*)&Vt[(nd * 16 + c15) * 72 + kk * 32 + quad * 8];
#pragma unroll
      for (int mi = 0; mi < 4; mi++)
#pragma unroll
        for (int nd = 0; nd < 4; nd++)
          oacc[mi][nd] = __builtin_amdgcn_mfma_f32_16x16x32_bf16(pf[mi], vf[nd], oacc[mi][nd], 0, 0, 0);
    }
  }

  // epilogue: normalize, write attn_out[b][s][h*64+d]
  const int b = bh >> 3, hh = bh & 7;
#pragma unroll
  for (int mi = 0; mi < 4; mi++) {
#pragma unroll
    for (int r = 0; r < 4; r++) {
      const int row = qrow0 + mi * 16 + quad * 4 + r;
      const float inv = 1.f / l_run[mi][r];
#pragma unroll
      for (int nd = 0; nd < 4; nd++) {
        const int d = nd * 16 + c15;
        o[((size_t)b * 1024 + row) * 512 + hh * 64 + d] = f2b(oacc[mi][nd][r] * inv);
      }
    }
  }
}

// ---------------- out proj (operands swapped: D[c][s]) + bias + residual ----------------
__global__ __launch_bounds__(256) void out_gemm(const u16* __restrict__ wo,
                                                const u16* __restrict__ attn,
                                                const float* __restrict__ ob,
                                                const float* __restrict__ x,
                                                float* __restrict__ out) {
  __shared__ u16 As[128 * 32];
  __shared__ u16 Bs[128 * 32];
  const int b = blockIdx.z;
  const int bm = blockIdx.x;   // c tiles: 0..3
  const int bn = blockIdx.y;   // s tiles: 0..7
  const int tid = threadIdx.x, lane = tid & 63, wid = tid >> 6;
  const int wm = wid & 1, wn = wid >> 1;
  const u16* gA = wo + (size_t)bm * 128 * 512;
  const u16* gB = attn + ((size_t)b * 1024 + bn * 128) * 512;

  const f32x4 fz = {0.f, 0.f, 0.f, 0.f};
  f32x4 acc[4][4];
#pragma unroll
  for (int i = 0; i < 4; i++)
#pragma unroll
    for (int j = 0; j < 4; j++) acc[i][j] = fz;

  const int r0 = lane >> 2;
  const int ch8 = (lane & 3) * 8;

  for (int kt = 0; kt < 16; ++kt) {
    __syncthreads();
#pragma unroll
    for (int j = 0; j < 2; ++j) {
      const int idx = wid * 2 + j;
      const int row = idx * 16 + r0;
      GLD16(gA + (size_t)row * 512 + kt * 32 + ch8, &As[idx * 512 + lane * 8]);
      GLD16(gB + (size_t)row * 512 + kt * 32 + ch8, &Bs[idx * 512 + lane * 8]);
    }
    __syncthreads();
    bf16x8 af[4], bf[4];
#pragma unroll
    for (int mi = 0; mi < 4; mi++)
      af[mi] = *(const bf16x8*)&As[(wm * 64 + mi * 16 + (lane & 15)) * 32 + (lane >> 4) * 8];
#pragma unroll
    for (int ni = 0; ni < 4; ni++)
      bf[ni] = *(const bf16x8*)&Bs[(wn * 64 + ni * 16 + (lane & 15)) * 32 + (lane >> 4) * 8];
#pragma unroll
    for (int mi = 0; mi < 4; mi++)
#pragma unroll
      for (int ni = 0; ni < 4; ni++)
        acc[mi][ni] = __builtin_amdgcn_mfma_f32_16x16x32_bf16(af[mi], bf[ni], acc[mi][ni], 0, 0, 0);
  }

  const int quad4 = (lane >> 4) << 2;
#pragma unroll
  for (int mi = 0; mi < 4; mi++) {
    const int c = bm * 128 + wm * 64 + mi * 16 + quad4;
#pragma unroll
    for (int ni = 0; ni < 4; ni++) {
      const int s = bn * 128 + wn * 64 + ni * 16 + (lane & 15);
#pragma unroll
      for (int r = 0; r < 4; r++) {
        const int cc = c + r;
        const size_t idx = ((size_t)b * 512 + cc) * 1024 + s;
        out[idx] = acc[mi][ni][r] + ob[cc] + x[idx];
      }
    }
  }
}

extern "C" void kernel_launch(void* const* d_in, const int* in_sizes, int n_in,
                              void* d_out, int out_size, void* d_ws, size_t ws_size,
                              hipStream_t stream) {
  const float* x      = (const float*)d_in[0];
  const float* gn_w   = (const float*)d_in[1];
  const float* gn_b   = (const float*)d_in[2];
  const float* proj_w = (const float*)d_in[3];
  const float* proj_b = (const float*)d_in[4];
  const float* out_w  = (const float*)d_in[5];
  const float* out_b  = (const float*)d_in[6];
  float* out = (float*)d_out;

  char* p = (char*)d_ws;
  u16* h    = (u16*)p; p += (size_t)16 * 1024 * 512 * 2;   // 16 MB
  u16* q    = (u16*)p; p += (size_t)16 * 8 * 1024 * 64 * 2;
  u16* k    = (u16*)p; p += (size_t)16 * 8 * 1024 * 64 * 2;
  u16* v    = (u16*)p; p += (size_t)16 * 8 * 1024 * 64 * 2;
  u16* attn = (u16*)p; p += (size_t)16 * 1024 * 512 * 2;
  u16* wq   = (u16*)p; p += (size_t)1536 * 512 * 2;
  u16* wo   = (u16*)p; p += (size_t)512 * 512 * 2;

  cvt_kernel<<<768, 256, 0, stream>>>(proj_w, wq, 196608);
  cvt_kernel<<<256, 256, 0, stream>>>(out_w, wo, 65536);
  gn_kernel<<<512, 256, 0, stream>>>(x, gn_w, gn_b, h);
  qkv_gemm<<<dim3(8, 12, 16), 256, 0, stream>>>(h, wq, proj_b, q, k, v);
  attn_kernel<<<dim3(128, 4, 1), 256, 0, stream>>>(q, k, v, attn);
  out_gemm<<<dim3(4, 8, 16), 256, 0, stream>>>(wo, attn, out_b, x, out);
}